// Round 9
// baseline (215.407 us; speedup 1.0000x reference)
//
#include <hip/hip_runtime.h>
#include <math.h>

#define DD 4096
#define EE 64
#define TAU 1e-4f
#define NEG_SENTINEL -1.0e30f
#define MAXFIX 4096

typedef __attribute__((ext_vector_type(8))) short short8v;
typedef __attribute__((ext_vector_type(4))) float f32x4;

union BF8 {
  uint4 u;
  short8v s;
};

__device__ __forceinline__ unsigned asu(float f) {
  union { float f; unsigned u; } v; v.f = f; return v.u;
}
__device__ __forceinline__ float asf(unsigned u) {
  union { unsigned u; float f; } v; v.u = u; return v.f;
}
__device__ __forceinline__ unsigned rne_hi(float x) {  // bf16 bits<<16
  unsigned u = asu(x);
  return (u + 0x7fffu + ((u >> 16) & 1u)) & 0xffff0000u;
}

// Split 8 f32 into hi/lo bf16 (RNE both): x = hi + lo + O(2^-17 |x|).
__device__ __forceinline__ void split8(const float x[8], uint4& hi, uint4& lo) {
  unsigned h[8], l[8];
#pragma unroll
  for (int j = 0; j < 8; j++) {
    h[j] = rne_hi(x[j]);
    l[j] = rne_hi(x[j] - asf(h[j]));
  }
  hi = make_uint4((h[0] >> 16) | h[1], (h[2] >> 16) | h[3],
                  (h[4] >> 16) | h[5], (h[6] >> 16) | h[7]);
  lo = make_uint4((l[0] >> 16) | l[1], (l[2] >> 16) | l[3],
                  (l[4] >> 16) | l[5], (l[6] >> 16) | l[7]);
}

// ---------------------------------------------------------------------------
// Kernel 0: pre-split gate_w (1 MB) into packed bf16 hi/lo planes [E][DD].
// Runs once per launch, ~1 us. Removes ALL B-side work from the gemm.
// ---------------------------------------------------------------------------
__global__ __launch_bounds__(256) void presplit_b(
    const float* __restrict__ gw, ushort* __restrict__ bhi,
    ushort* __restrict__ blo) {
  const int i = blockIdx.x * 256 + threadIdx.x;  // float4 index
  float4 v = ((const float4*)gw)[i];
  float x[4] = {v.x, v.y, v.z, v.w};
  ushort h[4], l[4];
#pragma unroll
  for (int j = 0; j < 4; j++) {
    unsigned hb = rne_hi(x[j]);
    h[j] = (ushort)(hb >> 16);
    l[j] = (ushort)(rne_hi(x[j] - asf(hb)) >> 16);
  }
  ((ushort4*)bhi)[i] = make_ushort4(h[0], h[1], h[2], h[3]);
  ((ushort4*)blo)[i] = make_ushort4(l[0], l[1], l[2], l[3]);
}

// ---------------------------------------------------------------------------
// Kernel 1 (R9): BARRIER-FREE streaming bf16-split MFMA partial GEMM.
// No LDS, no __syncthreads. Wave = 16 rows x 64 experts; block = 4 such
// waves (64 rows); grid = (nrows/64, KSPLIT). Per step (k += 32):
//   - 8 B-frag loads straight from global bf16 planes (L2-hot, 1KB/instr)
//   - A: 8 floats/lane from global, register prefetch depth 2
//   - split A in-register, 12 MFMAs (hh, hl, lh passes)
// Waves are fully independent -> vmcnt waits per-wave, hidden by TLP.
// ---------------------------------------------------------------------------
template <int KSPLIT>
__global__ __launch_bounds__(256, 4) void gemm_stream(
    const float* __restrict__ hidden, const ushort* __restrict__ bhi,
    const ushort* __restrict__ blo, float* __restrict__ part, int nrows) {
  const int lane = threadIdx.x & 63;
  const int wv = threadIdx.x >> 6;
  const int fr = lane & 15;
  const int fg = lane >> 4;  // 0..3
  const int m0 = blockIdx.x * 64 + wv * 16;
  const int kslice = DD / KSPLIT;
  const int nsteps = kslice / 32;
  const int k0 = blockIdx.y * kslice;

  // A: lane -> row m0+fr, k-octet fg (8 consecutive floats)
  const float* pA = hidden + (size_t)(m0 + fr) * DD + k0 + fg * 8;
  // B frags: lane -> expert fr (+nt*16), k-octet fg (8 consecutive bf16)
  const ushort* pH = bhi + (size_t)fr * DD + k0 + fg * 8;
  const ushort* pL = blo + (size_t)fr * DD + k0 + fg * 8;

  f32x4 zero4 = {0.f, 0.f, 0.f, 0.f};
  f32x4 acc[4];
#pragma unroll
  for (int nt = 0; nt < 4; nt++) acc[nt] = zero4;

  // rolling A registers: current, +1, +2
  float4 a0c, a1c, a0n, a1n, a0n2, a1n2;
  a0c = *(const float4*)(pA);
  a1c = *(const float4*)(pA + 4);
  a0n = *(const float4*)(pA + 32);
  a1n = *(const float4*)(pA + 36);
  a0n2 = *(const float4*)(pA + 64);
  a1n2 = *(const float4*)(pA + 68);

  for (int t = 0; t < nsteps; t++) {
    const int kq = t * 32;  // ushort offset for this step
    // issue B loads first (fly under the A-split VALU work)
    BF8 bh0, bh1, bh2, bh3, bl0, bl1, bl2, bl3;
    bh0.u = *(const uint4*)(pH + 0 * 16 * DD + kq);
    bh1.u = *(const uint4*)(pH + 1 * 16 * DD + kq);
    bh2.u = *(const uint4*)(pH + 2 * 16 * DD + kq);
    bh3.u = *(const uint4*)(pH + 3 * 16 * DD + kq);
    bl0.u = *(const uint4*)(pL + 0 * 16 * DD + kq);
    bl1.u = *(const uint4*)(pL + 1 * 16 * DD + kq);
    bl2.u = *(const uint4*)(pL + 2 * 16 * DD + kq);
    bl3.u = *(const uint4*)(pL + 3 * 16 * DD + kq);

    // split current A
    float xa[8] = {a0c.x, a0c.y, a0c.z, a0c.w, a1c.x, a1c.y, a1c.z, a1c.w};
    BF8 ah, al;
    split8(xa, ah.u, al.u);

    // roll A regs; prefetch t+3's data into the freed slot
    a0c = a0n; a1c = a1n;
    a0n = a0n2; a1n = a1n2;
    if (t + 3 < nsteps) {
      a0n2 = *(const float4*)(pA + (t + 3) * 32);
      a1n2 = *(const float4*)(pA + (t + 3) * 32 + 4);
    }

    // 12 MFMAs: hh, hl, lh passes (per-acc order fixed -> deterministic)
    acc[0] = __builtin_amdgcn_mfma_f32_16x16x32_bf16(ah.s, bh0.s, acc[0], 0, 0, 0);
    acc[1] = __builtin_amdgcn_mfma_f32_16x16x32_bf16(ah.s, bh1.s, acc[1], 0, 0, 0);
    acc[2] = __builtin_amdgcn_mfma_f32_16x16x32_bf16(ah.s, bh2.s, acc[2], 0, 0, 0);
    acc[3] = __builtin_amdgcn_mfma_f32_16x16x32_bf16(ah.s, bh3.s, acc[3], 0, 0, 0);
    acc[0] = __builtin_amdgcn_mfma_f32_16x16x32_bf16(ah.s, bl0.s, acc[0], 0, 0, 0);
    acc[1] = __builtin_amdgcn_mfma_f32_16x16x32_bf16(ah.s, bl1.s, acc[1], 0, 0, 0);
    acc[2] = __builtin_amdgcn_mfma_f32_16x16x32_bf16(ah.s, bl2.s, acc[2], 0, 0, 0);
    acc[3] = __builtin_amdgcn_mfma_f32_16x16x32_bf16(ah.s, bl3.s, acc[3], 0, 0, 0);
    acc[0] = __builtin_amdgcn_mfma_f32_16x16x32_bf16(al.s, bh0.s, acc[0], 0, 0, 0);
    acc[1] = __builtin_amdgcn_mfma_f32_16x16x32_bf16(al.s, bh1.s, acc[1], 0, 0, 0);
    acc[2] = __builtin_amdgcn_mfma_f32_16x16x32_bf16(al.s, bh2.s, acc[2], 0, 0, 0);
    acc[3] = __builtin_amdgcn_mfma_f32_16x16x32_bf16(al.s, bh3.s, acc[3], 0, 0, 0);
  }

  // partial logits part[ks][row][e]; C/D: row=(l>>4)*4+j, col=l&15
  float* dst = part + (size_t)blockIdx.y * nrows * EE;
#pragma unroll
  for (int j = 0; j < 4; j++) {
    const int r = m0 + fg * 4 + j;
#pragma unroll
    for (int nt = 0; nt < 4; nt++)
      dst[(size_t)r * EE + nt * 16 + fr] = acc[nt][j];
  }
}

// ---------------------------------------------------------------------------
// Kernel 2: reduce partials, sqrt(softplus), top-8 (lax.top_k tie-break),
// renormalize, scatter. Flags rows with margin < TAU for exact recompute.
// ---------------------------------------------------------------------------
__global__ __launch_bounds__(256) void topk_kernel(
    const float* __restrict__ part, const float* __restrict__ bias,
    float* __restrict__ out, int nrows, int ksplit, int* __restrict__ counter,
    int* __restrict__ list) {
  const int lane = threadIdx.x & 63;
  const int row = blockIdx.x * 4 + (threadIdx.x >> 6);

  float logit = 0.0f;
  for (int s = 0; s < ksplit; s++)
    logit += part[(size_t)s * nrows * EE + (size_t)row * EE + lane];

  float sp = (logit > 0.0f) ? (logit + log1pf(expf(-logit)))
                            : log1pf(expf(logit));
  float score = sqrtf(sp);
  float sel = score + bias[lane];

  float denom = 0.0f, v8 = 0.0f;
  bool chosen = false;
#pragma unroll
  for (int t = 0; t < 8; t++) {
    float v = sel;
    int idx = lane;
#pragma unroll
    for (int m = 1; m < 64; m <<= 1) {
      float ov = __shfl_xor(v, m, 64);
      int oi = __shfl_xor(idx, m, 64);
      if (ov > v || (ov == v && oi < idx)) { v = ov; idx = oi; }
    }
    float wscore = __shfl(score, idx, 64);
    denom += wscore;
    v8 = v;
    if (lane == idx) { chosen = true; sel = NEG_SENTINEL; }
  }
  float v9 = sel;
#pragma unroll
  for (int m = 1; m < 64; m <<= 1) v9 = fmaxf(v9, __shfl_xor(v9, m, 64));
  if (lane == 0 && (v8 - v9) < TAU) {
    int ix = atomicAdd(counter, 1);
    if (ix < MAXFIX) list[ix] = row;
  }

  denom = fmaxf(denom, 1e-12f);
  out[(size_t)row * EE + lane] = chosen ? (score / denom) : 0.0f;
  out[(size_t)nrows * EE + (size_t)row * EE + lane] = chosen ? 1.0f : 0.0f;
}

// ---------------------------------------------------------------------------
// Kernel 3a: exact-f32 partial dots for flagged rows, k-split 16 ways.
// ---------------------------------------------------------------------------
__global__ __launch_bounds__(256) void fixup_partial(
    const float* __restrict__ hidden, const float* __restrict__ gate_w,
    const int* __restrict__ counter, const int* __restrict__ list,
    float* __restrict__ part2) {
  __shared__ float red[EE][4];
  int cnt = *counter;
  if (cnt > MAXFIX) cnt = MAXFIX;
  const int total = cnt * 16;
  const int e = threadIdx.x & 63;
  const int q = threadIdx.x >> 6;
  for (int w = blockIdx.x; w < total; w += gridDim.x) {
    const int i = w >> 4;
    const int c = w & 15;
    const int row = list[i];
    const int kb = c * 256 + q * 64;
    const float* hp = hidden + (size_t)row * DD + kb;
    const float* wp = gate_w + (size_t)e * DD + kb;
    float s = 0.f;
#pragma unroll
    for (int k = 0; k < 64; k += 4) {
      float4 a = *(const float4*)(hp + k);
      float4 b = *(const float4*)(wp + k);
      s = fmaf(a.w, b.w, fmaf(a.z, b.z, fmaf(a.y, b.y, fmaf(a.x, b.x, s))));
    }
    red[e][q] = s;
    __syncthreads();
    if (threadIdx.x < EE)
      part2[(size_t)i * 1024 + threadIdx.x * 16 + c] =
          (red[threadIdx.x][0] + red[threadIdx.x][1]) +
          (red[threadIdx.x][2] + red[threadIdx.x][3]);
    __syncthreads();
  }
}

// ---------------------------------------------------------------------------
// Kernel 3b: sum the 16 chunks in fixed order, redo top-8 exactly, rewrite.
// ---------------------------------------------------------------------------
__global__ __launch_bounds__(256) void fixup_apply(
    const float* __restrict__ part2, const float* __restrict__ bias,
    const int* __restrict__ counter, const int* __restrict__ list,
    float* __restrict__ out, int nrows) {
  int cnt = *counter;
  if (cnt > MAXFIX) cnt = MAXFIX;
  const int lane = threadIdx.x & 63;
  const int wv = threadIdx.x >> 6;
  for (int i0 = blockIdx.x * 4; i0 < cnt; i0 += gridDim.x * 4) {
    const int i = i0 + wv;
    if (i >= cnt) continue;
    const int row = list[i];
    const float* pp = part2 + (size_t)i * 1024 + lane * 16;
    float logit = 0.f;
#pragma unroll
    for (int c = 0; c < 16; c++) logit += pp[c];

    float sp = (logit > 0.0f) ? (logit + log1pf(expf(-logit)))
                              : log1pf(expf(logit));
    float score = sqrtf(sp);
    float sel = score + bias[lane];
    float denom = 0.0f;
    bool chosen = false;
#pragma unroll
    for (int t = 0; t < 8; t++) {
      float v = sel;
      int idx = lane;
#pragma unroll
      for (int m = 1; m < 64; m <<= 1) {
        float ov = __shfl_xor(v, m, 64);
        int oi = __shfl_xor(idx, m, 64);
        if (ov > v || (ov == v && oi < idx)) { v = ov; idx = oi; }
      }
      float wscore = __shfl(score, idx, 64);
      denom += wscore;
      if (lane == idx) { chosen = true; sel = NEG_SENTINEL; }
    }
    denom = fmaxf(denom, 1e-12f);
    out[(size_t)row * EE + lane] = chosen ? (score / denom) : 0.0f;
    out[(size_t)nrows * EE + (size_t)row * EE + lane] = chosen ? 1.0f : 0.0f;
  }
}

// ---------------------------------------------------------------------------
extern "C" void kernel_launch(void* const* d_in, const int* in_sizes, int n_in,
                              void* d_out, int out_size, void* d_ws,
                              size_t ws_size, hipStream_t stream) {
  const float* hidden = (const float*)d_in[0];
  const float* gate_w = (const float*)d_in[1];
  const float* bias = (const float*)d_in[2];
  float* out = (float*)d_out;
  char* ws = (char*)d_ws;

  const int nrows = in_sizes[0] / DD;  // 16384

  // ws layout: part (<=32MB) | part2 @32MB (16MB) | Bhi @48MB | Blo @49MB
  float* part = (float*)ws;
  float* part2 = (float*)(ws + (size_t)32 * 1024 * 1024);
  ushort* bhi = (ushort*)(ws + (size_t)48 * 1024 * 1024);
  ushort* blo = (ushort*)(ws + (size_t)49 * 1024 * 1024);
  size_t tail = (ws_size - 4096) & ~(size_t)255;
  int* counter = (int*)(ws + tail);
  int* list = counter + 1;

  const size_t per = (size_t)nrows * EE * sizeof(float);  // 4 MiB
  const int ksplit = (ws_size >= (size_t)52 * 1024 * 1024) ? 8 : 4;

  hipMemsetAsync(counter, 0, sizeof(int), stream);
  presplit_b<<<dim3(EE * DD / 4 / 256), dim3(256), 0, stream>>>(gate_w, bhi,
                                                                blo);
  dim3 block(256);
  if (ksplit == 8)
    gemm_stream<8><<<dim3(nrows / 64, 8), block, 0, stream>>>(hidden, bhi, blo,
                                                              part, nrows);
  else
    gemm_stream<4><<<dim3(nrows / 64, 4), block, 0, stream>>>(hidden, bhi, blo,
                                                              part, nrows);
  topk_kernel<<<dim3(nrows / 4), block, 0, stream>>>(part, bias, out, nrows,
                                                     ksplit, counter, list);
  fixup_partial<<<dim3(2048), block, 0, stream>>>(hidden, gate_w, counter,
                                                  list, part2);
  fixup_apply<<<dim3(512), block, 0, stream>>>(part2, bias, counter, list, out,
                                               nrows);
}

// Round 10
// 206.925 us; speedup vs baseline: 1.0410x; 1.0410x over previous
//
#include <hip/hip_runtime.h>
#include <math.h>

#define DD 4096
#define EE 64
#define TAU 1e-4f
#define NEG_SENTINEL -1.0e30f
#define MAXFIX 4096

typedef __attribute__((ext_vector_type(8))) short short8v;
typedef __attribute__((ext_vector_type(4))) float f32x4;

union BF8 { uint4 u; short8v s; };

__device__ __forceinline__ unsigned asu(float f) {
  union { float f; unsigned u; } v; v.f = f; return v.u;
}
__device__ __forceinline__ float asf(unsigned u) {
  union { unsigned u; float f; } v; v.u = u; return v.f;
}
__device__ __forceinline__ unsigned rne_hi(float x) {  // bf16 bits<<16
  unsigned u = asu(x);
  return (u + 0x7fffu + ((u >> 16) & 1u)) & 0xffff0000u;
}
// Split 8 f32 into hi/lo bf16 (RNE both): x = hi + lo + O(2^-17 |x|).
__device__ __forceinline__ void split8(const float x[8], uint4& hi, uint4& lo) {
  unsigned h[8], l[8];
#pragma unroll
  for (int j = 0; j < 8; j++) {
    h[j] = rne_hi(x[j]);
    l[j] = rne_hi(x[j] - asf(h[j]));
  }
  hi = make_uint4((h[0] >> 16) | h[1], (h[2] >> 16) | h[3],
                  (h[4] >> 16) | h[5], (h[6] >> 16) | h[7]);
  lo = make_uint4((l[0] >> 16) | l[1], (l[2] >> 16) | l[3],
                  (l[4] >> 16) | l[5], (l[6] >> 16) | l[7]);
}
// global -> LDS direct copy, 16B/lane; LDS dest wave-uniform (HW adds l*16).
__device__ __forceinline__ void gload16(const void* g, void* l) {
  __builtin_amdgcn_global_load_lds(
      (const __attribute__((address_space(1))) uint32_t*)(uintptr_t)g,
      (__attribute__((address_space(3))) uint32_t*)(uint32_t)(uintptr_t)l, 16,
      0, 0);
}

// ---------------------------------------------------------------------------
// Kernel 0: pre-split gate_w into bf16 hi/lo, PRE-SWIZZLED chunk layout:
// chunk c (k in [64c,64c+64)): 16KB = [hi 8KB][lo 8KB]; within plane:
// byte(e, slot) = e*128 + ((slot ^ (e&7))<<4), slot = (k>>3)&7.
// gload_lds then stages it linearly and reads use the same XOR (rule 21).
// ---------------------------------------------------------------------------
__global__ __launch_bounds__(256) void presplit_b(const float* __restrict__ gw,
                                                  char* __restrict__ bglob) {
  const int t = blockIdx.x * 256 + threadIdx.x;  // 64 e x 512 slots = 32768
  const int e = t >> 9;
  const int sidx = t & 511;
  const int c = sidx >> 3;
  const int slot = sidx & 7;
  const float* src = gw + e * DD + sidx * 8;
  float4 v0 = *(const float4*)src;
  float4 v1 = *(const float4*)(src + 4);
  float x[8] = {v0.x, v0.y, v0.z, v0.w, v1.x, v1.y, v1.z, v1.w};
  uint4 hi, lo;
  split8(x, hi, lo);
  char* base = bglob + c * 16384 + e * 128 + ((slot ^ (e & 7)) << 4);
  *(uint4*)base = hi;
  *(uint4*)(base + 8192) = lo;
}

// ---------------------------------------------------------------------------
// Kernel 1 (R10): fused GEMM + top-k. grid = nrows/64 = 256 (1 block/CU).
// Block: 256 thr = 4 waves; wave owns 16 rows x 64 experts (24 MFMAs/chunk).
// LDS 64KB: A-ring 2 x 16KB (f32, R8 source-swizzle) @0; B-ring 2 x 16KB
// (pre-split bf16 hi/lo) @32768. Per chunk t: issue STAGE(t+1) [8 gload/wave]
// -> s_waitcnt vmcnt(8) [counted: t+1 stays IN FLIGHT] -> s_barrier ->
// ds_reads + split8(A) + 24 MFMA -> lgkmcnt(0) -> s_barrier. No vmcnt(0) in
// the loop (T4). Wrap-chunk stages land in a dead buffer, drained after.
// Epilogue: logits -> LDS -> per-wave top-8 (R6-proven) -> out.
// ---------------------------------------------------------------------------
__global__ __launch_bounds__(256, 1) void gemm_topk(
    const float* __restrict__ hidden, const char* __restrict__ bglob,
    const float* __restrict__ bias, float* __restrict__ out,
    int* __restrict__ counter, int* __restrict__ list, int nrows) {
  __shared__ __align__(16) char smem[65536];
  const int tid = threadIdx.x;
  const int lane = tid & 63;
  const int wv = tid >> 6;
  const int fr = lane & 15;
  const int fg = lane >> 4;
  const int m0 = blockIdx.x * 64;

  // A staging sources (R8-proven pre-swizzle: phys slot = src slot ^ (row&15))
  const float* srcA[4];
#pragma unroll
  for (int i = 0; i < 4; i++) {
    const int rloc = 4 * i + (lane >> 4);      // 0..15 within wave
    const int s = (lane & 15) ^ rloc;          // source 16B slot
    srcA[i] = hidden + (size_t)(m0 + 16 * wv + rloc) * DD + s * 4;
  }
  const char* srcB = bglob + wv * 4096 + lane * 16;

  auto stage = [&](int chunk) {
    const int buf = chunk & 1;
    char* ad = smem + buf * 16384 + wv * 4096;
    char* bd = smem + 32768 + buf * 16384 + wv * 4096;
    const char* bs = srcB + chunk * 16384;
#pragma unroll
    for (int i = 0; i < 4; i++) {
      gload16(srcA[i] + chunk * 64, ad + i * 1024);
      gload16(bs + i * 1024, bd + i * 1024);
    }
  };

  f32x4 zero4 = {0.f, 0.f, 0.f, 0.f};
  f32x4 acc[4];
#pragma unroll
  for (int nt = 0; nt < 4; nt++) acc[nt] = zero4;

  const int arow = (16 * wv + fr) * 256;

  stage(0);
  for (int t = 0; t < 64; t++) {
    stage((t + 1) & 63);  // uniform issue; t=63 wraps into dead buffer
    asm volatile("s_waitcnt vmcnt(8)" ::: "memory");  // chunk t ready; t+1 in flight
    __builtin_amdgcn_s_barrier();
    asm volatile("" ::: "memory");

    const char* Ab = smem + (t & 1) * 16384;
    const char* Bb = smem + 32768 + (t & 1) * 16384;
#pragma unroll
    for (int c = 0; c < 2; c++) {
      float4 a0 = *(const float4*)(Ab + arow + (((c * 8 + fg * 2 + 0) ^ fr) << 4));
      float4 a1 = *(const float4*)(Ab + arow + (((c * 8 + fg * 2 + 1) ^ fr) << 4));
      float xa[8] = {a0.x, a0.y, a0.z, a0.w, a1.x, a1.y, a1.z, a1.w};
      BF8 ah, al;
      split8(xa, ah.u, al.u);
      BF8 bh[4], bl[4];
#pragma unroll
      for (int nt = 0; nt < 4; nt++) {
        const int boff = (nt * 16 + fr) * 128 + (((c * 4 + fg) ^ (fr & 7)) << 4);
        bh[nt].u = *(const uint4*)(Bb + boff);
        bl[nt].u = *(const uint4*)(Bb + 8192 + boff);
      }
#pragma unroll
      for (int nt = 0; nt < 4; nt++)
        acc[nt] = __builtin_amdgcn_mfma_f32_16x16x32_bf16(ah.s, bh[nt].s,
                                                          acc[nt], 0, 0, 0);
#pragma unroll
      for (int nt = 0; nt < 4; nt++)
        acc[nt] = __builtin_amdgcn_mfma_f32_16x16x32_bf16(ah.s, bl[nt].s,
                                                          acc[nt], 0, 0, 0);
#pragma unroll
      for (int nt = 0; nt < 4; nt++)
        acc[nt] = __builtin_amdgcn_mfma_f32_16x16x32_bf16(al.s, bh[nt].s,
                                                          acc[nt], 0, 0, 0);
    }
    asm volatile("s_waitcnt lgkmcnt(0)" ::: "memory");
    __builtin_amdgcn_s_barrier();
    asm volatile("" ::: "memory");
  }

  // drain the wrap-chunk garbage stages before reusing LDS
  asm volatile("s_waitcnt vmcnt(0)" ::: "memory");
  __builtin_amdgcn_s_barrier();
  asm volatile("" ::: "memory");

  // logits -> LDS [64][68] f32
  float* Lg = (float*)smem;
#pragma unroll
  for (int nt = 0; nt < 4; nt++)
#pragma unroll
    for (int j = 0; j < 4; j++)
      Lg[(wv * 16 + fg * 4 + j) * 68 + nt * 16 + fr] = acc[nt][j];
  asm volatile("s_waitcnt lgkmcnt(0)" ::: "memory");
  __builtin_amdgcn_s_barrier();
  asm volatile("" ::: "memory");

  // per-wave top-8 over 16 rows (R6-proven semantics incl. tie-break)
  const float bl_ = bias[lane];
  for (int rr = 0; rr < 16; rr++) {
    const int row = wv * 16 + rr;
    const float logit = Lg[row * 68 + lane];
    float sp = (logit > 0.0f) ? (logit + log1pf(expf(-logit)))
                              : log1pf(expf(logit));
    float score = sqrtf(sp);
    float sel = score + bl_;
    float denom = 0.0f, v8 = 0.0f;
    bool chosen = false;
#pragma unroll
    for (int k = 0; k < 8; k++) {
      float v = sel;
      int idx = lane;
#pragma unroll
      for (int m = 1; m < 64; m <<= 1) {
        float ov = __shfl_xor(v, m, 64);
        int oi = __shfl_xor(idx, m, 64);
        if (ov > v || (ov == v && oi < idx)) { v = ov; idx = oi; }
      }
      float wscore = __shfl(score, idx, 64);
      denom += wscore;
      v8 = v;
      if (lane == idx) { chosen = true; sel = NEG_SENTINEL; }
    }
    float v9 = sel;
#pragma unroll
    for (int m = 1; m < 64; m <<= 1) v9 = fmaxf(v9, __shfl_xor(v9, m, 64));
    const int grow = m0 + row;
    if (lane == 0 && (v8 - v9) < TAU) {
      int ix = atomicAdd(counter, 1);
      if (ix < MAXFIX) list[ix] = grow;
    }
    denom = fmaxf(denom, 1e-12f);
    out[(size_t)grow * EE + lane] = chosen ? (score / denom) : 0.0f;
    out[(size_t)nrows * EE + (size_t)grow * EE + lane] = chosen ? 1.0f : 0.0f;
  }
}

// ---------------------------------------------------------------------------
// Kernel 2a: exact-f32 partial dots for flagged rows, k-split 16 ways.
// ---------------------------------------------------------------------------
__global__ __launch_bounds__(256) void fixup_partial(
    const float* __restrict__ hidden, const float* __restrict__ gate_w,
    const int* __restrict__ counter, const int* __restrict__ list,
    float* __restrict__ part2) {
  __shared__ float red[EE][4];
  int cnt = *counter;
  if (cnt > MAXFIX) cnt = MAXFIX;
  const int total = cnt * 16;
  const int e = threadIdx.x & 63;
  const int q = threadIdx.x >> 6;
  for (int w = blockIdx.x; w < total; w += gridDim.x) {
    const int i = w >> 4;
    const int c = w & 15;
    const int row = list[i];
    const int kb = c * 256 + q * 64;
    const float* hp = hidden + (size_t)row * DD + kb;
    const float* wp = gate_w + (size_t)e * DD + kb;
    float s = 0.f;
#pragma unroll
    for (int k = 0; k < 64; k += 4) {
      float4 a = *(const float4*)(hp + k);
      float4 b = *(const float4*)(wp + k);
      s = fmaf(a.w, b.w, fmaf(a.z, b.z, fmaf(a.y, b.y, fmaf(a.x, b.x, s))));
    }
    red[e][q] = s;
    __syncthreads();
    if (threadIdx.x < EE)
      part2[(size_t)i * 1024 + threadIdx.x * 16 + c] =
          (red[threadIdx.x][0] + red[threadIdx.x][1]) +
          (red[threadIdx.x][2] + red[threadIdx.x][3]);
    __syncthreads();
  }
}

// ---------------------------------------------------------------------------
// Kernel 2b: sum the 16 chunks in fixed order, redo top-8 exactly, rewrite.
// ---------------------------------------------------------------------------
__global__ __launch_bounds__(256) void fixup_apply(
    const float* __restrict__ part2, const float* __restrict__ bias,
    const int* __restrict__ counter, const int* __restrict__ list,
    float* __restrict__ out, int nrows) {
  int cnt = *counter;
  if (cnt > MAXFIX) cnt = MAXFIX;
  const int lane = threadIdx.x & 63;
  const int wv = threadIdx.x >> 6;
  for (int i0 = blockIdx.x * 4; i0 < cnt; i0 += gridDim.x * 4) {
    const int i = i0 + wv;
    if (i >= cnt) continue;
    const int row = list[i];
    const float* pp = part2 + (size_t)i * 1024 + lane * 16;
    float logit = 0.f;
#pragma unroll
    for (int c = 0; c < 16; c++) logit += pp[c];
    float sp = (logit > 0.0f) ? (logit + log1pf(expf(-logit)))
                              : log1pf(expf(logit));
    float score = sqrtf(sp);
    float sel = score + bias[lane];
    float denom = 0.0f;
    bool chosen = false;
#pragma unroll
    for (int k = 0; k < 8; k++) {
      float v = sel;
      int idx = lane;
#pragma unroll
      for (int m = 1; m < 64; m <<= 1) {
        float ov = __shfl_xor(v, m, 64);
        int oi = __shfl_xor(idx, m, 64);
        if (ov > v || (ov == v && oi < idx)) { v = ov; idx = oi; }
      }
      float wscore = __shfl(score, idx, 64);
      denom += wscore;
      if (lane == idx) { chosen = true; sel = NEG_SENTINEL; }
    }
    denom = fmaxf(denom, 1e-12f);
    out[(size_t)row * EE + lane] = chosen ? (score / denom) : 0.0f;
    out[(size_t)nrows * EE + (size_t)row * EE + lane] = chosen ? 1.0f : 0.0f;
  }
}

// ---------------------------------------------------------------------------
extern "C" void kernel_launch(void* const* d_in, const int* in_sizes, int n_in,
                              void* d_out, int out_size, void* d_ws,
                              size_t ws_size, hipStream_t stream) {
  const float* hidden = (const float*)d_in[0];
  const float* gate_w = (const float*)d_in[1];
  const float* bias = (const float*)d_in[2];
  float* out = (float*)d_out;
  char* ws = (char*)d_ws;

  const int nrows = in_sizes[0] / DD;  // 16384

  // ws: bglob @0 (1MB) | part2 @2MB (16MB) | counter/list @tail
  char* bglob = ws;
  float* part2 = (float*)(ws + (size_t)2 * 1024 * 1024);
  size_t tail = (ws_size - 65536) & ~(size_t)255;
  int* counter = (int*)(ws + tail);
  int* list = counter + 1;

  hipMemsetAsync(counter, 0, sizeof(int), stream);
  presplit_b<<<dim3(128), dim3(256), 0, stream>>>(gate_w, bglob);
  gemm_topk<<<dim3(nrows / 64), dim3(256), 0, stream>>>(
      hidden, bglob, bias, out, counter, list, nrows);
  fixup_partial<<<dim3(2048), dim3(256), 0, stream>>>(hidden, gate_w, counter,
                                                      list, part2);
  fixup_apply<<<dim3(512), dim3(256), 0, stream>>>(part2, bias, counter, list,
                                                   out, nrows);
}

// Round 11
// 133.891 us; speedup vs baseline: 1.6088x; 1.5455x over previous
//
#include <hip/hip_runtime.h>
#include <math.h>

#define DD 4096
#define EE 64
#define TAU 1e-4f
#define NEG_SENTINEL -1.0e30f
#define MAXFIX 4096

typedef __attribute__((ext_vector_type(8))) short short8v;
typedef __attribute__((ext_vector_type(4))) float f32x4;

union BF8 { uint4 u; short8v s; };

__device__ __forceinline__ unsigned asu(float f) {
  union { float f; unsigned u; } v; v.f = f; return v.u;
}
__device__ __forceinline__ float asf(unsigned u) {
  union { unsigned u; float f; } v; v.u = u; return v.f;
}
__device__ __forceinline__ unsigned rne_hi(float x) {  // bf16 bits<<16
  unsigned u = asu(x);
  return (u + 0x7fffu + ((u >> 16) & 1u)) & 0xffff0000u;
}
// Split 8 f32 into hi/lo bf16 (RNE both): x = hi + lo + O(2^-17 |x|).
__device__ __forceinline__ void split8(const float x[8], uint4& hi, uint4& lo) {
  unsigned h[8], l[8];
#pragma unroll
  for (int j = 0; j < 8; j++) {
    h[j] = rne_hi(x[j]);
    l[j] = rne_hi(x[j] - asf(h[j]));
  }
  hi = make_uint4((h[0] >> 16) | h[1], (h[2] >> 16) | h[3],
                  (h[4] >> 16) | h[5], (h[6] >> 16) | h[7]);
  lo = make_uint4((l[0] >> 16) | l[1], (l[2] >> 16) | l[3],
                  (l[4] >> 16) | l[5], (l[6] >> 16) | l[7]);
}

// ---------------------------------------------------------------------------
// Kernel 0: pre-split gate_w into bf16 hi/lo with the gemm's exact read
// layout: bglob[ks][chunk][hi|lo][e][slot16B]; chunk = 32 k, slot = 8 bf16.
// Each gemm B-frag load is then one contiguous 1KB wave window (coalesced).
// ---------------------------------------------------------------------------
__global__ __launch_bounds__(256) void presplit_b(const float* __restrict__ gw,
                                                  char* __restrict__ bglob) {
  const int t = blockIdx.x * 256 + threadIdx.x;  // 64 e x 512 octets
  const int e = t >> 9;
  const int o = t & 511;       // k-octet (8 floats)
  const int ks = o >> 6;       // k-slice (512 k each)
  const int ow = o & 63;       // octet within slice
  const int ck = ow >> 2;      // 32-k chunk within slice
  const int slot = ow & 3;
  const float* src = gw + e * DD + o * 8;
  float4 v0 = *(const float4*)src;
  float4 v1 = *(const float4*)(src + 4);
  float x[8] = {v0.x, v0.y, v0.z, v0.w, v1.x, v1.y, v1.z, v1.w};
  uint4 hi, lo;
  split8(x, hi, lo);
  char* dst = bglob + ks * 131072 + ck * 8192 + e * 64 + slot * 16;
  *(uint4*)dst = hi;
  *(uint4*)(dst + 4096) = lo;
}

// ---------------------------------------------------------------------------
// Kernel 1 (R11): no-LDS, no-barrier streaming bf16-split MFMA partial GEMM.
// Wave = 64 rows (mt=4) x 64 experts; block = 4 waves (256 rows); grid =
// (nrows/256, KSPLIT=8) = 512 blocks = 2 blocks/CU = 2 waves/SIMD @ <=256
// VGPR. Per 32-k step: 8 B loads (1KB contiguous wave-window each, L2-hot)
// + 8 A loads (16 rows x 128B lines) prefetched one full step ahead
// (ping-pong regs, fully unrolled -> static indexing), 4 split8, 48 MFMA.
// 48 MFMA / 16 VMEM per step; waves fully independent.
// ---------------------------------------------------------------------------
template <int KSPLIT>
__global__ __launch_bounds__(256, 2) void gemm_stream(
    const float* __restrict__ hidden, const char* __restrict__ bglob,
    float* __restrict__ part, int nrows) {
  const int lane = threadIdx.x & 63;
  const int wv = threadIdx.x >> 6;
  const int fr = lane & 15;
  const int fg = lane >> 4;  // 0..3
  const int m0 = blockIdx.x * 256 + wv * 64;
  const int kslice = DD / KSPLIT;   // 512
  const int nsteps = kslice / 32;   // 16
  const int k0 = blockIdx.y * kslice;

  const float* pA[4];
#pragma unroll
  for (int mt = 0; mt < 4; mt++)
    pA[mt] = hidden + (size_t)(m0 + mt * 16 + fr) * DD + k0 + fg * 8;
  const char* pB = bglob + blockIdx.y * 131072 + fr * 64 + fg * 16;

  f32x4 zero4 = {0.f, 0.f, 0.f, 0.f};
  f32x4 acc[4][4];
#pragma unroll
  for (int mt = 0; mt < 4; mt++)
#pragma unroll
    for (int nt = 0; nt < 4; nt++) acc[mt][nt] = zero4;

  float4 a[2][4][2];  // [pingpong][mt][half]
  uint4 b[2][8];      // [pingpong][plane*4+nt]

#define LOADA(S, T)                                                  \
  _Pragma("unroll") for (int mt = 0; mt < 4; mt++) {                 \
    a[S][mt][0] = *(const float4*)(pA[mt] + (T) * 32);               \
    a[S][mt][1] = *(const float4*)(pA[mt] + (T) * 32 + 4);           \
  }
#define LOADB(S, T)                                                  \
  _Pragma("unroll") for (int i = 0; i < 8; i++) {                    \
    b[S][i] = *(const uint4*)(pB + (T) * 8192 + (i >> 2) * 4096 +    \
                              (i & 3) * 1024);                       \
  }

  LOADA(0, 0)
  LOADB(0, 0)

#pragma unroll
  for (int t = 0; t < 16; t++) {
    const int cur = t & 1, nxt = (t & 1) ^ 1;
    if (t + 1 < 16) {
      LOADA(nxt, t + 1)
      LOADB(nxt, t + 1)
    }
    // split A (frees a[cur])
    BF8 ah[4], al[4];
#pragma unroll
    for (int mt = 0; mt < 4; mt++) {
      float xa[8] = {a[cur][mt][0].x, a[cur][mt][0].y, a[cur][mt][0].z,
                     a[cur][mt][0].w, a[cur][mt][1].x, a[cur][mt][1].y,
                     a[cur][mt][1].z, a[cur][mt][1].w};
      split8(xa, ah[mt].u, al[mt].u);
    }
    BF8 bh[4], bl[4];
#pragma unroll
    for (int nt = 0; nt < 4; nt++) {
      bh[nt].u = b[cur][nt];
      bl[nt].u = b[cur][4 + nt];
    }
    // 48 MFMAs, pass-outer (per-acc order hh->hl->lh, deterministic)
#pragma unroll
    for (int nt = 0; nt < 4; nt++)
#pragma unroll
      for (int mt = 0; mt < 4; mt++)
        acc[mt][nt] = __builtin_amdgcn_mfma_f32_16x16x32_bf16(
            ah[mt].s, bh[nt].s, acc[mt][nt], 0, 0, 0);
#pragma unroll
    for (int nt = 0; nt < 4; nt++)
#pragma unroll
      for (int mt = 0; mt < 4; mt++)
        acc[mt][nt] = __builtin_amdgcn_mfma_f32_16x16x32_bf16(
            ah[mt].s, bl[nt].s, acc[mt][nt], 0, 0, 0);
#pragma unroll
    for (int nt = 0; nt < 4; nt++)
#pragma unroll
      for (int mt = 0; mt < 4; mt++)
        acc[mt][nt] = __builtin_amdgcn_mfma_f32_16x16x32_bf16(
            al[mt].s, bh[nt].s, acc[mt][nt], 0, 0, 0);
  }
#undef LOADA
#undef LOADB

  // partial logits part[ks][row][e]; C/D: row=(l>>4)*4+j, col=l&15
  float* dst = part + (size_t)blockIdx.y * nrows * EE;
#pragma unroll
  for (int mt = 0; mt < 4; mt++)
#pragma unroll
    for (int j = 0; j < 4; j++) {
      const int r = m0 + mt * 16 + fg * 4 + j;
#pragma unroll
      for (int nt = 0; nt < 4; nt++)
        dst[(size_t)r * EE + nt * 16 + fr] = acc[mt][nt][j];
    }
}

// ---------------------------------------------------------------------------
// Kernel 2: reduce partials, sqrt(softplus), top-8 (lax.top_k tie-break),
// renormalize, scatter. Flags rows with margin < TAU for exact recompute.
// ---------------------------------------------------------------------------
__global__ __launch_bounds__(256) void topk_kernel(
    const float* __restrict__ part, const float* __restrict__ bias,
    float* __restrict__ out, int nrows, int ksplit, int* __restrict__ counter,
    int* __restrict__ list) {
  const int lane = threadIdx.x & 63;
  const int row = blockIdx.x * 4 + (threadIdx.x >> 6);

  float logit = 0.0f;
  for (int s = 0; s < ksplit; s++)
    logit += part[(size_t)s * nrows * EE + (size_t)row * EE + lane];

  float sp = (logit > 0.0f) ? (logit + log1pf(expf(-logit)))
                            : log1pf(expf(logit));
  float score = sqrtf(sp);
  float sel = score + bias[lane];

  float denom = 0.0f, v8 = 0.0f;
  bool chosen = false;
#pragma unroll
  for (int t = 0; t < 8; t++) {
    float v = sel;
    int idx = lane;
#pragma unroll
    for (int m = 1; m < 64; m <<= 1) {
      float ov = __shfl_xor(v, m, 64);
      int oi = __shfl_xor(idx, m, 64);
      if (ov > v || (ov == v && oi < idx)) { v = ov; idx = oi; }
    }
    float wscore = __shfl(score, idx, 64);
    denom += wscore;
    v8 = v;
    if (lane == idx) { chosen = true; sel = NEG_SENTINEL; }
  }
  float v9 = sel;
#pragma unroll
  for (int m = 1; m < 64; m <<= 1) v9 = fmaxf(v9, __shfl_xor(v9, m, 64));
  if (lane == 0 && (v8 - v9) < TAU) {
    int ix = atomicAdd(counter, 1);
    if (ix < MAXFIX) list[ix] = row;
  }

  denom = fmaxf(denom, 1e-12f);
  out[(size_t)row * EE + lane] = chosen ? (score / denom) : 0.0f;
  out[(size_t)nrows * EE + (size_t)row * EE + lane] = chosen ? 1.0f : 0.0f;
}

// ---------------------------------------------------------------------------
// Kernel 3a: exact-f32 partial dots for flagged rows, k-split 16 ways.
// ---------------------------------------------------------------------------
__global__ __launch_bounds__(256) void fixup_partial(
    const float* __restrict__ hidden, const float* __restrict__ gate_w,
    const int* __restrict__ counter, const int* __restrict__ list,
    float* __restrict__ part2) {
  __shared__ float red[EE][4];
  int cnt = *counter;
  if (cnt > MAXFIX) cnt = MAXFIX;
  const int total = cnt * 16;
  const int e = threadIdx.x & 63;
  const int q = threadIdx.x >> 6;
  for (int w = blockIdx.x; w < total; w += gridDim.x) {
    const int i = w >> 4;
    const int c = w & 15;
    const int row = list[i];
    const int kb = c * 256 + q * 64;
    const float* hp = hidden + (size_t)row * DD + kb;
    const float* wp = gate_w + (size_t)e * DD + kb;
    float s = 0.f;
#pragma unroll
    for (int k = 0; k < 64; k += 4) {
      float4 aa = *(const float4*)(hp + k);
      float4 bb = *(const float4*)(wp + k);
      s = fmaf(aa.w, bb.w, fmaf(aa.z, bb.z, fmaf(aa.y, bb.y, fmaf(aa.x, bb.x, s))));
    }
    red[e][q] = s;
    __syncthreads();
    if (threadIdx.x < EE)
      part2[(size_t)i * 1024 + threadIdx.x * 16 + c] =
          (red[threadIdx.x][0] + red[threadIdx.x][1]) +
          (red[threadIdx.x][2] + red[threadIdx.x][3]);
    __syncthreads();
  }
}

// ---------------------------------------------------------------------------
// Kernel 3b: sum the 16 chunks in fixed order, redo top-8 exactly, rewrite.
// ---------------------------------------------------------------------------
__global__ __launch_bounds__(256) void fixup_apply(
    const float* __restrict__ part2, const float* __restrict__ bias,
    const int* __restrict__ counter, const int* __restrict__ list,
    float* __restrict__ out, int nrows) {
  int cnt = *counter;
  if (cnt > MAXFIX) cnt = MAXFIX;
  const int lane = threadIdx.x & 63;
  const int wv = threadIdx.x >> 6;
  for (int i0 = blockIdx.x * 4; i0 < cnt; i0 += gridDim.x * 4) {
    const int i = i0 + wv;
    if (i >= cnt) continue;
    const int row = list[i];
    const float* pp = part2 + (size_t)i * 1024 + lane * 16;
    float logit = 0.f;
#pragma unroll
    for (int c = 0; c < 16; c++) logit += pp[c];
    float sp = (logit > 0.0f) ? (logit + log1pf(expf(-logit)))
                              : log1pf(expf(logit));
    float score = sqrtf(sp);
    float sel = score + bias[lane];
    float denom = 0.0f;
    bool chosen = false;
#pragma unroll
    for (int k = 0; k < 8; k++) {
      float v = sel;
      int idx = lane;
#pragma unroll
      for (int m = 1; m < 64; m <<= 1) {
        float ov = __shfl_xor(v, m, 64);
        int oi = __shfl_xor(idx, m, 64);
        if (ov > v || (ov == v && oi < idx)) { v = ov; idx = oi; }
      }
      float wscore = __shfl(score, idx, 64);
      denom += wscore;
      if (lane == idx) { chosen = true; sel = NEG_SENTINEL; }
    }
    denom = fmaxf(denom, 1e-12f);
    out[(size_t)row * EE + lane] = chosen ? (score / denom) : 0.0f;
    out[(size_t)nrows * EE + (size_t)row * EE + lane] = chosen ? 1.0f : 0.0f;
  }
}

// ---------------------------------------------------------------------------
extern "C" void kernel_launch(void* const* d_in, const int* in_sizes, int n_in,
                              void* d_out, int out_size, void* d_ws,
                              size_t ws_size, hipStream_t stream) {
  const float* hidden = (const float*)d_in[0];
  const float* gate_w = (const float*)d_in[1];
  const float* bias = (const float*)d_in[2];
  float* out = (float*)d_out;
  char* ws = (char*)d_ws;

  const int nrows = in_sizes[0] / DD;  // 16384

  // ws: bglob @0 (1MB) | part @2MB (32MB) | part2 @34MB (16MB) | tail ctr
  char* bglob = ws;
  float* part = (float*)(ws + (size_t)2 * 1024 * 1024);
  float* part2 = (float*)(ws + (size_t)34 * 1024 * 1024);
  size_t tail = (ws_size - 65536) & ~(size_t)255;
  int* counter = (int*)(ws + tail);
  int* list = counter + 1;

  hipMemsetAsync(counter, 0, sizeof(int), stream);
  presplit_b<<<dim3(128), dim3(256), 0, stream>>>(gate_w, bglob);
  gemm_stream<8><<<dim3(nrows / 256, 8), dim3(256), 0, stream>>>(hidden, bglob,
                                                                 part, nrows);
  topk_kernel<<<dim3(nrows / 4), dim3(256), 0, stream>>>(part, bias, out,
                                                         nrows, 8, counter,
                                                         list);
  fixup_partial<<<dim3(2048), dim3(256), 0, stream>>>(hidden, gate_w, counter,
                                                      list, part2);
  fixup_apply<<<dim3(512), dim3(256), 0, stream>>>(part2, bias, counter, list,
                                                   out, nrows);
}

// Round 12
// 116.865 us; speedup vs baseline: 1.8432x; 1.1457x over previous
//
#include <hip/hip_runtime.h>
#include <math.h>

#define DD 4096
#define EE 64
#define TAU 1e-4f
#define NEG_SENTINEL -1.0e30f
#define MAXFIX 4096

typedef __attribute__((ext_vector_type(8))) short short8v;
typedef __attribute__((ext_vector_type(4))) float f32x4;

union BF8 { uint4 u; short8v s; };

__device__ __forceinline__ unsigned asu(float f) {
  union { float f; unsigned u; } v; v.f = f; return v.u;
}
__device__ __forceinline__ float asf(unsigned u) {
  union { unsigned u; float f; } v; v.u = u; return v.f;
}
__device__ __forceinline__ unsigned rne_hi(float x) {  // bf16 bits<<16
  unsigned u = asu(x);
  return (u + 0x7fffu + ((u >> 16) & 1u)) & 0xffff0000u;
}
// Split 8 f32 into hi/lo bf16 (RNE both): x = hi + lo + O(2^-17 |x|).
__device__ __forceinline__ void split8(const float x[8], uint4& hi, uint4& lo) {
  unsigned h[8], l[8];
#pragma unroll
  for (int j = 0; j < 8; j++) {
    h[j] = rne_hi(x[j]);
    l[j] = rne_hi(x[j] - asf(h[j]));
  }
  hi = make_uint4((h[0] >> 16) | h[1], (h[2] >> 16) | h[3],
                  (h[4] >> 16) | h[5], (h[6] >> 16) | h[7]);
  lo = make_uint4((l[0] >> 16) | l[1], (l[2] >> 16) | l[3],
                  (l[4] >> 16) | l[5], (l[6] >> 16) | l[7]);
}
// global -> LDS direct copy, 16B/lane; LDS dest wave-uniform (HW adds l*16).
__device__ __forceinline__ void gload16(const void* g, void* l) {
  __builtin_amdgcn_global_load_lds(
      (const __attribute__((address_space(1))) uint32_t*)(uintptr_t)g,
      (__attribute__((address_space(3))) uint32_t*)(uint32_t)(uintptr_t)l, 16,
      0, 0);
}

// ---------------------------------------------------------------------------
// Kernel 0: pre-split gate_w into bf16 hi/lo in the gemm's exact STAGED
// layout: bglob[slice(1024k)][step(32k)][plane hi|lo][e][slot16B], with the
// read-side swizzle baked in: source k-octet o (8 bf16) of expert e lands at
// slot o ^ ((e>>1)&3). The gemm stages each 8KB step verbatim (linear dest,
// rule 21) and reads slot fg ^ ((fr>>1)&3).
// ---------------------------------------------------------------------------
__global__ __launch_bounds__(256) void presplit_b(const float* __restrict__ gw,
                                                  char* __restrict__ bglob) {
  const int t = blockIdx.x * 256 + threadIdx.x;  // 64 e x 512 octets
  const int e = t >> 9;
  const int o = t & 511;          // k-octet (8 floats) within the row
  const int slice = o >> 7;       // 128 octets per 1024-k slice
  const int ow = o & 127;
  const int step = ow >> 2;       // 4 octets per 32-k step
  const int oslot = ow & 3;
  const float* src = gw + e * DD + o * 8;
  float4 v0 = *(const float4*)src;
  float4 v1 = *(const float4*)(src + 4);
  float x[8] = {v0.x, v0.y, v0.z, v0.w, v1.x, v1.y, v1.z, v1.w};
  uint4 hi, lo;
  split8(x, hi, lo);
  char* dst = bglob + (size_t)slice * 262144 + step * 8192 + e * 64 +
              ((oslot ^ ((e >> 1) & 3)) << 4);
  *(uint4*)dst = hi;
  *(uint4*)(dst + 4096) = lo;
}

// ---------------------------------------------------------------------------
// Kernel 1 (R12): R3's proven staging pipeline + MFMA compute.
// Tile 64 rows x 64 experts x BK=32. 4 waves; wave = 16 rows (mt=1, nt=4).
// LDS 32KB: 2 bufs x {A 8KB f32, B 8KB bf16 hi/lo} -> 4 blocks/CU; grid
// (nrows/64, 4) = 1024 = fully resident.
// A: gload_lds, [64r][128B], source pre-swizzle slot^( row&7 ); read at
//    (2fg+j)^(fr&7)  -> even 8-lanes-per-bank-quad (conflict-free b128).
// B: staged verbatim from pre-swizzled bglob; read slot fg^((fr>>1)&3).
// Per step: stage(t+1) [4 gload/wave] -> 10 ds_read_b128 + 2 split8 +
// 12 MFMA -> __syncthreads (drains; t+1 loads flew during compute).
// ---------------------------------------------------------------------------
__global__ __launch_bounds__(256, 4) void gemm_mfma(
    const float* __restrict__ hidden, const char* __restrict__ bglob,
    float* __restrict__ part, int nrows) {
  __shared__ __align__(16) char smem[32768];  // [buf][A 8K | B 8K]

  const int lane = threadIdx.x & 63;
  const int wv = threadIdx.x >> 6;
  const int fr = lane & 15;
  const int fg = lane >> 4;  // 0..3
  const int m0 = blockIdx.x * 64;
  const int slice = blockIdx.y;          // ksplit = 4, kslice = 1024
  const int k0 = slice * 1024;

  // A sources: wave wv stages rows 16wv..+15; instr i covers rows 8i..8i+7
  // (wave-local). lane l -> row rloc = 8i+(l>>3), source slot (l&7)^(rloc&7).
  const float* srcA[2];
#pragma unroll
  for (int i = 0; i < 2; i++) {
    const int rloc = 8 * i + (lane >> 3);
    const int s = (lane & 7) ^ (rloc & 7);
    srcA[i] = hidden + (size_t)(m0 + 16 * wv + rloc) * DD + k0 + s * 4;
  }
  const char* srcB = bglob + (size_t)slice * 262144 + wv * 2048 + lane * 16;

  auto stage = [&](int t) {
    const int buf = t & 1;
    char* ad = smem + buf * 16384 + wv * 2048;
    char* bd = smem + buf * 16384 + 8192 + wv * 2048;
#pragma unroll
    for (int i = 0; i < 2; i++) {
      gload16(srcA[i] + t * 32, ad + i * 1024);
      gload16(srcB + t * 8192 + i * 1024, bd + i * 1024);
    }
  };

  f32x4 zero4 = {0.f, 0.f, 0.f, 0.f};
  f32x4 acc[4];
#pragma unroll
  for (int nt = 0; nt < 4; nt++) acc[nt] = zero4;

  const int abase = wv * 2048 + fr * 128;
  const int bslot = (fg ^ ((fr >> 1) & 3)) << 4;

  stage(0);
  __syncthreads();

  for (int t = 0; t < 32; t++) {
    if (t + 1 < 32) stage(t + 1);
    const char* Ab = smem + (t & 1) * 16384;
    const char* Bb = Ab + 8192;
    // A frag: 8 consecutive k-floats via 2 swizzled b128 reads
    float4 a0 = *(const float4*)(Ab + abase + (((2 * fg + 0) ^ (fr & 7)) << 4));
    float4 a1 = *(const float4*)(Ab + abase + (((2 * fg + 1) ^ (fr & 7)) << 4));
    float xa[8] = {a0.x, a0.y, a0.z, a0.w, a1.x, a1.y, a1.z, a1.w};
    BF8 ah, al;
    split8(xa, ah.u, al.u);
    BF8 bh[4], bl[4];
#pragma unroll
    for (int nt = 0; nt < 4; nt++) {
      const int boff = (nt * 16 + fr) * 64 + bslot;
      bh[nt].u = *(const uint4*)(Bb + boff);
      bl[nt].u = *(const uint4*)(Bb + 4096 + boff);
    }
    // 12 MFMAs, pass-outer (per-acc order hh->hl->lh, deterministic)
#pragma unroll
    for (int nt = 0; nt < 4; nt++)
      acc[nt] = __builtin_amdgcn_mfma_f32_16x16x32_bf16(ah.s, bh[nt].s,
                                                        acc[nt], 0, 0, 0);
#pragma unroll
    for (int nt = 0; nt < 4; nt++)
      acc[nt] = __builtin_amdgcn_mfma_f32_16x16x32_bf16(ah.s, bl[nt].s,
                                                        acc[nt], 0, 0, 0);
#pragma unroll
    for (int nt = 0; nt < 4; nt++)
      acc[nt] = __builtin_amdgcn_mfma_f32_16x16x32_bf16(al.s, bh[nt].s,
                                                        acc[nt], 0, 0, 0);
    __syncthreads();
  }

  // partial logits part[slice][row][e]; C/D row=fg*4+j, col=fr
  float* dst = part + (size_t)slice * nrows * EE;
#pragma unroll
  for (int j = 0; j < 4; j++) {
    const int r = m0 + 16 * wv + fg * 4 + j;
#pragma unroll
    for (int nt = 0; nt < 4; nt++)
      dst[(size_t)r * EE + nt * 16 + fr] = acc[nt][j];
  }
}

// ---------------------------------------------------------------------------
// Kernel 2: reduce partials, sqrt(softplus), top-8 (lax.top_k tie-break),
// renormalize, scatter. Flags rows with margin < TAU for exact recompute.
// ---------------------------------------------------------------------------
__global__ __launch_bounds__(256) void topk_kernel(
    const float* __restrict__ part, const float* __restrict__ bias,
    float* __restrict__ out, int nrows, int ksplit, int* __restrict__ counter,
    int* __restrict__ list) {
  const int lane = threadIdx.x & 63;
  const int row = blockIdx.x * 4 + (threadIdx.x >> 6);

  float logit = 0.0f;
  for (int s = 0; s < ksplit; s++)
    logit += part[(size_t)s * nrows * EE + (size_t)row * EE + lane];

  float sp = (logit > 0.0f) ? (logit + log1pf(expf(-logit)))
                            : log1pf(expf(logit));
  float score = sqrtf(sp);
  float sel = score + bias[lane];

  float denom = 0.0f, v8 = 0.0f;
  bool chosen = false;
#pragma unroll
  for (int t = 0; t < 8; t++) {
    float v = sel;
    int idx = lane;
#pragma unroll
    for (int m = 1; m < 64; m <<= 1) {
      float ov = __shfl_xor(v, m, 64);
      int oi = __shfl_xor(idx, m, 64);
      if (ov > v || (ov == v && oi < idx)) { v = ov; idx = oi; }
    }
    float wscore = __shfl(score, idx, 64);
    denom += wscore;
    v8 = v;
    if (lane == idx) { chosen = true; sel = NEG_SENTINEL; }
  }
  float v9 = sel;
#pragma unroll
  for (int m = 1; m < 64; m <<= 1) v9 = fmaxf(v9, __shfl_xor(v9, m, 64));
  if (lane == 0 && (v8 - v9) < TAU) {
    int ix = atomicAdd(counter, 1);
    if (ix < MAXFIX) list[ix] = row;
  }

  denom = fmaxf(denom, 1e-12f);
  out[(size_t)row * EE + lane] = chosen ? (score / denom) : 0.0f;
  out[(size_t)nrows * EE + (size_t)row * EE + lane] = chosen ? 1.0f : 0.0f;
}

// ---------------------------------------------------------------------------
// Kernel 3a: exact-f32 partial dots for flagged rows, k-split 16 ways.
// ---------------------------------------------------------------------------
__global__ __launch_bounds__(256) void fixup_partial(
    const float* __restrict__ hidden, const float* __restrict__ gate_w,
    const int* __restrict__ counter, const int* __restrict__ list,
    float* __restrict__ part2) {
  __shared__ float red[EE][4];
  int cnt = *counter;
  if (cnt > MAXFIX) cnt = MAXFIX;
  const int total = cnt * 16;
  const int e = threadIdx.x & 63;
  const int q = threadIdx.x >> 6;
  for (int w = blockIdx.x; w < total; w += gridDim.x) {
    const int i = w >> 4;
    const int c = w & 15;
    const int row = list[i];
    const int kb = c * 256 + q * 64;
    const float* hp = hidden + (size_t)row * DD + kb;
    const float* wp = gate_w + (size_t)e * DD + kb;
    float s = 0.f;
#pragma unroll
    for (int k = 0; k < 64; k += 4) {
      float4 aa = *(const float4*)(hp + k);
      float4 bb = *(const float4*)(wp + k);
      s = fmaf(aa.w, bb.w, fmaf(aa.z, bb.z, fmaf(aa.y, bb.y, fmaf(aa.x, bb.x, s))));
    }
    red[e][q] = s;
    __syncthreads();
    if (threadIdx.x < EE)
      part2[(size_t)i * 1024 + threadIdx.x * 16 + c] =
          (red[threadIdx.x][0] + red[threadIdx.x][1]) +
          (red[threadIdx.x][2] + red[threadIdx.x][3]);
    __syncthreads();
  }
}

// ---------------------------------------------------------------------------
// Kernel 3b: sum the 16 chunks in fixed order, redo top-8 exactly, rewrite.
// ---------------------------------------------------------------------------
__global__ __launch_bounds__(256) void fixup_apply(
    const float* __restrict__ part2, const float* __restrict__ bias,
    const int* __restrict__ counter, const int* __restrict__ list,
    float* __restrict__ out, int nrows) {
  int cnt = *counter;
  if (cnt > MAXFIX) cnt = MAXFIX;
  const int lane = threadIdx.x & 63;
  const int wv = threadIdx.x >> 6;
  for (int i0 = blockIdx.x * 4; i0 < cnt; i0 += gridDim.x * 4) {
    const int i = i0 + wv;
    if (i >= cnt) continue;
    const int row = list[i];
    const float* pp = part2 + (size_t)i * 1024 + lane * 16;
    float logit = 0.f;
#pragma unroll
    for (int c = 0; c < 16; c++) logit += pp[c];
    float sp = (logit > 0.0f) ? (logit + log1pf(expf(-logit)))
                              : log1pf(expf(logit));
    float score = sqrtf(sp);
    float sel = score + bias[lane];
    float denom = 0.0f;
    bool chosen = false;
#pragma unroll
    for (int k = 0; k < 8; k++) {
      float v = sel;
      int idx = lane;
#pragma unroll
      for (int m = 1; m < 64; m <<= 1) {
        float ov = __shfl_xor(v, m, 64);
        int oi = __shfl_xor(idx, m, 64);
        if (ov > v || (ov == v && oi < idx)) { v = ov; idx = oi; }
      }
      float wscore = __shfl(score, idx, 64);
      denom += wscore;
      if (lane == idx) { chosen = true; sel = NEG_SENTINEL; }
    }
    denom = fmaxf(denom, 1e-12f);
    out[(size_t)row * EE + lane] = chosen ? (score / denom) : 0.0f;
    out[(size_t)nrows * EE + (size_t)row * EE + lane] = chosen ? 1.0f : 0.0f;
  }
}

// ---------------------------------------------------------------------------
extern "C" void kernel_launch(void* const* d_in, const int* in_sizes, int n_in,
                              void* d_out, int out_size, void* d_ws,
                              size_t ws_size, hipStream_t stream) {
  const float* hidden = (const float*)d_in[0];
  const float* gate_w = (const float*)d_in[1];
  const float* bias = (const float*)d_in[2];
  float* out = (float*)d_out;
  char* ws = (char*)d_ws;

  const int nrows = in_sizes[0] / DD;  // 16384

  // ws: bglob @0 (1MB) | part @2MB (16MB) | part2 @20MB (16MB) | tail ctr
  char* bglob = ws;
  float* part = (float*)(ws + (size_t)2 * 1024 * 1024);
  float* part2 = (float*)(ws + (size_t)20 * 1024 * 1024);
  size_t tail = (ws_size - 65536) & ~(size_t)255;
  int* counter = (int*)(ws + tail);
  int* list = counter + 1;

  hipMemsetAsync(counter, 0, sizeof(int), stream);
  presplit_b<<<dim3(128), dim3(256), 0, stream>>>(gate_w, bglob);
  gemm_mfma<<<dim3(nrows / 64, 4), dim3(256), 0, stream>>>(hidden, bglob, part,
                                                           nrows);
  topk_kernel<<<dim3(nrows / 4), dim3(256), 0, stream>>>(part, bias, out,
                                                         nrows, 4, counter,
                                                         list);
  fixup_partial<<<dim3(2048), dim3(256), 0, stream>>>(hidden, gate_w, counter,
                                                      list, part2);
  fixup_apply<<<dim3(512), dim3(256), 0, stream>>>(part2, bias, counter, list,
                                                   out, nrows);
}